// Round 1
// baseline (786.136 us; speedup 1.0000x reference)
//
#include <hip/hip_runtime.h>

// GridRNN B=4, S=T=128, H=256, D=3 — MFMA, LDS-only barrier, deep x-prefetch.
// 64 wgs x 512 thr (8 waves, N=32/wave); 16 chains/wg (X-diagonals / Y-rows).
// Per step: [16x256]@[256x256]^T x2 via mfma_f32_16x16x32_f16.
// LDS A-frag layout: entry e = f*64 + q*16 + m  <=>  A[m][k=f*32+q*8..+7],
// which is ALSO n-major chunks: entry tid <=> (m=tid&15, n0=(tid>>4)*8).
//
// R6 changes vs R5 (783 us):
//  - __syncthreads -> s_waitcnt lgkmcnt(0) + raw s_barrier. __syncthreads
//    drains vmcnt(0) per step, i.e. waits for h-store retirement + the
//    x-prefetch load every step (~3500cy stall/step). No intra-kernel
//    consumer of the global stores exists, so LDS-only ordering suffices.
//  - depth-4 register FIFO for x-inputs: LDS write of x(s+1) consumes a
//    load issued 4 steps earlier -> vmcnt wait is trivially satisfied.
//    d==0 FIFO holds raw f32 (convert at consume) so no early vmcnt wait.
//  - kernel specialized on depth d (template) -> uniform load paths,
//    precise compiler waitcnt counts.

#define SS 128
#define TT 128
#define HH 256
#define GRID_ELEMS ((size_t)4 * 128 * 128 * 256)

typedef _Float16 half8 __attribute__((ext_vector_type(8)));
typedef float float4v __attribute__((ext_vector_type(4)));

__device__ __forceinline__ float fast_tanh(float x) {
    float e = __expf(2.0f * x);
    return 1.0f - 2.0f / (e + 1.0f);
}

__device__ __forceinline__ unsigned short f2hbits(float x) {
    _Float16 h = (_Float16)x;
    return __builtin_bit_cast(unsigned short, h);
}

// LDS-only workgroup barrier: orders LDS ops across waves but does NOT
// drain vmcnt — global stores retire lazily, prefetch loads stay in
// flight across steps. "memory" clobber pins compiler reordering.
__device__ __forceinline__ void lds_barrier() {
    asm volatile("s_waitcnt lgkmcnt(0)" ::: "memory");
    __builtin_amdgcn_s_barrier();
}

template <int DI>
__device__ __forceinline__ void grid_rnn_body(
    const float* __restrict__ src, const float* __restrict__ trg,
    const float* __restrict__ Wx_ih, const float* __restrict__ Wx_hh,
    const float* __restrict__ bx_ih, const float* __restrict__ bx_hh,
    const float* __restrict__ Wy_ih, const float* __restrict__ Wy_hh,
    const float* __restrict__ by_ih, const float* __restrict__ by_hh,
    float* __restrict__ out, unsigned short* __restrict__ ws, int use_ws)
{
    __shared__ half8 aX[2][512];   // x-input A-frags, double buffered
    __shared__ half8 aH[2][512];   // h-state A-frags, double buffered

    const int tid  = threadIdx.x;
    const int lane = tid & 63;
    const int wv   = tid >> 6;     // wave 0..7 -> N-slice n0 = 32*wv
    const int quad = lane >> 4;
    const int l15  = lane & 15;

    const int bid  = blockIdx.x;   // 0..63
    const int isY  = bid >= 32;
    const int g    = isY ? bid - 32 : bid;
    const int b    = g >> 3;       // batch
    const int c0   = (g & 7) << 4; // first chain of the 16-chain group
    const int slot = isY;

    const float* Wih = (isY ? Wy_ih : Wx_ih) + (size_t)DI * HH * HH;
    const float* Whh = (isY ? Wy_hh : Wx_hh) + (size_t)DI * HH * HH;
    const float* bih = (isY ? by_ih : bx_ih) + DI * HH;
    const float* bhh = (isY ? by_hh : bx_hh) + DI * HH;
    unsigned short* wsg = ws + (size_t)isY * GRID_ELEMS;

    const int n_0 = (wv << 5) + l15;   // tile-0 column
    const int n_1 = n_0 + 16;          // tile-1 column

    // ---- B fragments (weights), register/AGPR-resident.
    half8 Bih0[8], Bih1[8], Bhh0[8], Bhh1[8];
    {
        auto ldfrag = [&](const float* rowp, int k) -> half8 {
            const float4v u0 = *(const float4v*)(rowp + k);
            const float4v u1 = *(const float4v*)(rowp + k + 4);
            half8 v;
#pragma unroll
            for (int e = 0; e < 4; ++e) { v[e] = (_Float16)u0[e]; v[4 + e] = (_Float16)u1[e]; }
            return v;
        };
        const float* r0i = Wih + (size_t)n_0 * HH;
        const float* r1i = Wih + (size_t)n_1 * HH;
        const float* r0h = Whh + (size_t)n_0 * HH;
        const float* r1h = Whh + (size_t)n_1 * HH;
#pragma unroll
        for (int f = 0; f < 8; ++f) {
            const int k = (f << 5) + (quad << 3);
            Bih0[f] = ldfrag(r0i, k);
            Bih1[f] = ldfrag(r1i, k);
            Bhh0[f] = ldfrag(r0h, k);
            Bhh1[f] = ldfrag(r1h, k);
        }
    }
    const float bias0 = bih[n_0] + bhh[n_0];
    const float bias1 = bih[n_1] + bhh[n_1];

    // ---- staging geometry: thread tid owns A-frag entry tid:
    // m=tid&15, k0=(tid>>4)*8.
    const int cm  = tid & 15;
    const int ck0 = (tid >> 4) << 3;
    const int chc = c0 + cm;

    // immediate stage (init + non-ws fallback only)
    auto stage_now = [&](int sn) -> half8 {
        const int i = isY ? chc : sn;
        const int j = isY ? sn : ((chc + sn) & 127);
        const size_t cell = (size_t)(b * SS + i) * TT + j;
        half8 v;
        if (DI == 0) {
            const float* row = isY ? (trg + (size_t)(b * TT + j) * HH)
                                   : (src + (size_t)(b * SS + i) * HH);
            const float4v u0 = *(const float4v*)(row + ck0);
            const float4v u1 = *(const float4v*)(row + ck0 + 4);
#pragma unroll
            for (int e = 0; e < 4; ++e) { v[e] = (_Float16)u0[e]; v[4 + e] = (_Float16)u1[e]; }
        } else if (use_ws) {
            v = *(const half8*)(wsg + cell * HH + ck0);
        } else {
            const float* row = out + cell * 2 * HH + (size_t)slot * HH + ck0;
            const float4v u0 = *(const float4v*)(row);
            const float4v u1 = *(const float4v*)(row + 4);
#pragma unroll
            for (int e = 0; e < 4; ++e) { v[e] = (_Float16)u0[e]; v[4 + e] = (_Float16)u1[e]; }
        }
        return v;
    };

    // ---- depth-4 x-prefetch FIFO.
    // Invariant: entering step s (u = s&3), slot u holds x(s+1).
    half8  qh[4];               // DI>0 && use_ws: f16 ws rows
    float4v qa[4], qb[4];       // DI==0: raw f32 (convert at consume)

    auto fifo_issue = [&](int u, int t) {
        const int i = isY ? chc : t;
        const int j = isY ? t : ((chc + t) & 127);
        if constexpr (DI == 0) {
            const float* row = isY ? (trg + (size_t)(b * TT + j) * HH)
                                   : (src + (size_t)(b * SS + i) * HH);
            qa[u] = *(const float4v*)(row + ck0);
            qb[u] = *(const float4v*)(row + ck0 + 4);
        } else {
            if (use_ws) {
                const size_t cell = (size_t)(b * SS + i) * TT + j;
                qh[u] = *(const half8*)(wsg + cell * HH + ck0);
            }
        }
    };

    auto fifo_take = [&](int u, int snext) -> half8 {
        half8 v;
        if constexpr (DI == 0) {
#pragma unroll
            for (int e = 0; e < 4; ++e) { v[e] = (_Float16)qa[u][e]; v[4 + e] = (_Float16)qb[u][e]; }
        } else {
            if (use_ws) {
                v = qh[u];
            } else {
                if (snext > 127) snext = 127;
                v = stage_now(snext);   // slow fallback path only
            }
        }
        return v;
    };

    // ---- coalesced h-store: thread tid stores chunk (cell m=tid&15, k0)
    auto store_h = [&](int sp, int bufi) {
        const half8 v = aH[bufi][tid];
        const int i = isY ? chc : sp;
        const int j = isY ? sp : ((chc + sp) & 127);
        const size_t cell = (size_t)(b * SS + i) * TT + j;
        if (DI == 2 || !use_ws) {
            float* p = out + cell * 2 * HH + (size_t)slot * HH + ck0;
            float4v u0, u1;
#pragma unroll
            for (int e = 0; e < 4; ++e) { u0[e] = (float)v[e]; u1[e] = (float)v[4 + e]; }
            *(float4v*)p = u0;
            *(float4v*)(p + 4) = u1;
        }
        if (DI < 2 && use_ws) {
            *(half8*)(wsg + cell * HH + ck0) = v;
        }
    };

    // ---- init: zero h-state buf 0, stage X(0), prime the FIFO.
    {
        half8 z;
#pragma unroll
        for (int e = 0; e < 8; ++e) z[e] = (_Float16)0.f;
        aH[0][tid] = z;
    }
    aX[0][tid] = stage_now(0);
#pragma unroll
    for (int u = 0; u < 4; ++u) fifo_issue(u, u + 1);   // x(1)..x(4)
    __syncthreads();   // one full drain at init only

    const int cellbase0 = ((n_0 >> 5) << 6) + (((n_0 >> 3) & 3) << 4);
    const int cellbase1 = ((n_1 >> 5) << 6) + (((n_1 >> 3) & 3) << 4);

    int buf = 0;
    for (int s4 = 0; s4 < 128; s4 += 4) {
#pragma unroll
        for (int u = 0; u < 4; ++u) {
            const int s = s4 + u;

            // h(s-1) -> global; stores retire lazily (no vmcnt drain at barrier)
            if (s > 0) store_h(s - 1, buf);

            // x(s+1) -> LDS; its load was issued 4 steps ago (vmcnt wait ~free)
            aX[buf ^ 1][tid] = fifo_take(u, s + 1);

            // refill FIFO slot u with x(s+5) (clamped; tail value never read)
            {
                int t = s + 5; if (t > 127) t = 127;
                fifo_issue(u, t);
            }

            // A-frags from LDS (lane-contiguous b128, conflict-free pattern)
            half8 axr[8], ahr[8];
#pragma unroll
            for (int f = 0; f < 8; ++f) {
                axr[f] = aX[buf][(f << 6) + lane];
                ahr[f] = aH[buf][(f << 6) + lane];
            }

            // D = Xin@Wih^T + Hprev@Whh^T + bias (4 independent 8-deep chains)
            float4v ax0 = {bias0, bias0, bias0, bias0};
            float4v ax1 = {bias1, bias1, bias1, bias1};
            float4v ah0 = {0.f, 0.f, 0.f, 0.f};
            float4v ah1 = {0.f, 0.f, 0.f, 0.f};
#pragma unroll
            for (int f = 0; f < 8; ++f) {
                ax0 = __builtin_amdgcn_mfma_f32_16x16x32_f16(axr[f], Bih0[f], ax0, 0, 0, 0);
                ax1 = __builtin_amdgcn_mfma_f32_16x16x32_f16(axr[f], Bih1[f], ax1, 0, 0, 0);
                ah0 = __builtin_amdgcn_mfma_f32_16x16x32_f16(ahr[f], Bhh0[f], ah0, 0, 0, 0);
                ah1 = __builtin_amdgcn_mfma_f32_16x16x32_f16(ahr[f], Bhh1[f], ah1, 0, 0, 0);
            }

            // tanh + scatter h(s) into aH[buf^1]
            unsigned short* aHu = (unsigned short*)aH[buf ^ 1];
#pragma unroll
            for (int r = 0; r < 4; ++r) {
                const float h0 = fast_tanh(ax0[r] + ah0[r]);
                const float h1 = fast_tanh(ax1[r] + ah1[r]);
                const int m = (quad << 2) + r;
                aHu[((cellbase0 + m) << 3) + (n_0 & 7)] = f2hbits(h0);
                aHu[((cellbase1 + m) << 3) + (n_1 & 7)] = f2hbits(h1);
            }

            lds_barrier();   // LDS-only: lgkmcnt(0) + s_barrier, NO vmcnt drain
            buf ^= 1;
        }
    }

    // epilogue: store h(127)
    store_h(127, buf);
}

extern "C" __global__ void __launch_bounds__(512, 2)
grid_rnn_d0(const float* __restrict__ src, const float* __restrict__ trg,
            const float* __restrict__ Wx_ih, const float* __restrict__ Wx_hh,
            const float* __restrict__ bx_ih, const float* __restrict__ bx_hh,
            const float* __restrict__ Wy_ih, const float* __restrict__ Wy_hh,
            const float* __restrict__ by_ih, const float* __restrict__ by_hh,
            float* __restrict__ out, unsigned short* __restrict__ ws, int use_ws)
{
    grid_rnn_body<0>(src, trg, Wx_ih, Wx_hh, bx_ih, bx_hh,
                     Wy_ih, Wy_hh, by_ih, by_hh, out, ws, use_ws);
}

extern "C" __global__ void __launch_bounds__(512, 2)
grid_rnn_d1(const float* __restrict__ src, const float* __restrict__ trg,
            const float* __restrict__ Wx_ih, const float* __restrict__ Wx_hh,
            const float* __restrict__ bx_ih, const float* __restrict__ bx_hh,
            const float* __restrict__ Wy_ih, const float* __restrict__ Wy_hh,
            const float* __restrict__ by_ih, const float* __restrict__ by_hh,
            float* __restrict__ out, unsigned short* __restrict__ ws, int use_ws)
{
    grid_rnn_body<1>(src, trg, Wx_ih, Wx_hh, bx_ih, bx_hh,
                     Wy_ih, Wy_hh, by_ih, by_hh, out, ws, use_ws);
}

extern "C" __global__ void __launch_bounds__(512, 2)
grid_rnn_d2(const float* __restrict__ src, const float* __restrict__ trg,
            const float* __restrict__ Wx_ih, const float* __restrict__ Wx_hh,
            const float* __restrict__ bx_ih, const float* __restrict__ bx_hh,
            const float* __restrict__ Wy_ih, const float* __restrict__ Wy_hh,
            const float* __restrict__ by_ih, const float* __restrict__ by_hh,
            float* __restrict__ out, unsigned short* __restrict__ ws, int use_ws)
{
    grid_rnn_body<2>(src, trg, Wx_ih, Wx_hh, bx_ih, bx_hh,
                     Wy_ih, Wy_hh, by_ih, by_hh, out, ws, use_ws);
}

extern "C" void kernel_launch(void* const* d_in, const int* in_sizes, int n_in,
                              void* d_out, int out_size, void* d_ws, size_t ws_size,
                              hipStream_t stream) {
    const float* src   = (const float*)d_in[0];
    const float* trg   = (const float*)d_in[1];
    const float* Wx_ih = (const float*)d_in[2];
    const float* Wx_hh = (const float*)d_in[3];
    const float* bx_ih = (const float*)d_in[4];
    const float* bx_hh = (const float*)d_in[5];
    const float* Wy_ih = (const float*)d_in[6];
    const float* Wy_hh = (const float*)d_in[7];
    const float* by_ih = (const float*)d_in[8];
    const float* by_hh = (const float*)d_in[9];
    float* out = (float*)d_out;
    unsigned short* ws = (unsigned short*)d_ws;

    const size_t need = 2 * GRID_ELEMS * sizeof(unsigned short);  // 67.1 MB
    const int use_ws = (ws_size >= need) ? 1 : 0;

    hipLaunchKernelGGL(grid_rnn_d0, dim3(64), dim3(512), 0, stream,
                       src, trg, Wx_ih, Wx_hh, bx_ih, bx_hh,
                       Wy_ih, Wy_hh, by_ih, by_hh, out, ws, use_ws);
    hipLaunchKernelGGL(grid_rnn_d1, dim3(64), dim3(512), 0, stream,
                       src, trg, Wx_ih, Wx_hh, bx_ih, bx_hh,
                       Wy_ih, Wy_hh, by_ih, by_hh, out, ws, use_ws);
    hipLaunchKernelGGL(grid_rnn_d2, dim3(64), dim3(512), 0, stream,
                       src, trg, Wx_ih, Wx_hh, bx_ih, bx_hh,
                       Wy_ih, Wy_hh, by_ih, by_hh, out, ws, use_ws);
}

// Round 2
// 646.434 us; speedup vs baseline: 1.2161x; 1.2161x over previous
//
#include <hip/hip_runtime.h>

// GridRNN B=4, S=T=128, H=256, D=3 — MFMA, LDS-only barrier, deep x-prefetch.
// R7: 256 wgs x 512 thr, 4 chains/wg (was 64 wgs x 16 chains).
//   Per-step latency, not throughput, bounds this kernel (128 serial steps).
//   MFMA count per wg per step is fixed at 256 (N=256/16 x K=512/32) no
//   matter how many chains the wg owns, so spreading 1024 chains over 256
//   CUs keeps the matrix-pipe cost/CU constant (~1242cy) while cutting LDS
//   reads, staging, tanh and store work 4x -> step should approach the
//   MFMA floor. A-matrix rows 4..15 are handled by MIRRORING: lanes with
//   (lane&15)>=4 read row (lane&3) from LDS (broadcast, bank-free); the
//   resulting D rows 4..15 are duplicates of rows 0..3 and are ignored
//   (matmul rows are independent).
//
// LDS A layout (C=4): entry e = f*16 + q*4 + m  <=>  A[m][k=f*32+q*8..+7];
// staging thread tid<128 owns entry tid (m=tid&3, k0=(tid>>2)*8) — identity.

#define SS 128
#define TT 128
#define HH 256
#define GRID_ELEMS ((size_t)4 * 128 * 128 * 256)

typedef _Float16 half8 __attribute__((ext_vector_type(8)));
typedef float float4v __attribute__((ext_vector_type(4)));

__device__ __forceinline__ float fast_tanh(float x) {
    float e = __expf(2.0f * x);
    return 1.0f - 2.0f / (e + 1.0f);
}

__device__ __forceinline__ unsigned short f2hbits(float x) {
    _Float16 h = (_Float16)x;
    return __builtin_bit_cast(unsigned short, h);
}

// LDS-only workgroup barrier: orders LDS ops across waves but does NOT
// drain vmcnt — global stores retire lazily, prefetch loads stay in
// flight across steps. "memory" clobber pins compiler reordering.
__device__ __forceinline__ void lds_barrier() {
    asm volatile("s_waitcnt lgkmcnt(0)" ::: "memory");
    __builtin_amdgcn_s_barrier();
}

template <int DI>
__device__ __forceinline__ void grid_rnn_body(
    const float* __restrict__ src, const float* __restrict__ trg,
    const float* __restrict__ Wx_ih, const float* __restrict__ Wx_hh,
    const float* __restrict__ bx_ih, const float* __restrict__ bx_hh,
    const float* __restrict__ Wy_ih, const float* __restrict__ Wy_hh,
    const float* __restrict__ by_ih, const float* __restrict__ by_hh,
    float* __restrict__ out, unsigned short* __restrict__ ws, int use_ws)
{
    __shared__ half8 aX[2][128];   // x-input A-frags (4x256 f16), dbuf
    __shared__ half8 aH[2][128];   // h-state A-frags (4x256 f16), dbuf

    const int tid  = threadIdx.x;
    const int lane = tid & 63;
    const int wv   = tid >> 6;     // wave 0..7 -> N-slice n0 = 32*wv
    const int quad = lane >> 4;
    const int l15  = lane & 15;

    const int bid  = blockIdx.x;   // 0..255
    const int isY  = bid >= 128;
    const int g    = isY ? bid - 128 : bid;
    const int b    = g >> 5;       // batch
    const int c0   = (g & 31) << 2; // first chain of the 4-chain group
    const int slot = isY;

    const float* Wih = (isY ? Wy_ih : Wx_ih) + (size_t)DI * HH * HH;
    const float* Whh = (isY ? Wy_hh : Wx_hh) + (size_t)DI * HH * HH;
    const float* bih = (isY ? by_ih : bx_ih) + DI * HH;
    const float* bhh = (isY ? by_hh : bx_hh) + DI * HH;
    unsigned short* wsg = ws + (size_t)isY * GRID_ELEMS;

    const int n_0 = (wv << 5) + l15;   // tile-0 column
    const int n_1 = n_0 + 16;          // tile-1 column

    // ---- B fragments (weights), register/AGPR-resident.
    half8 Bih0[8], Bih1[8], Bhh0[8], Bhh1[8];
    {
        auto ldfrag = [&](const float* rowp, int k) -> half8 {
            const float4v u0 = *(const float4v*)(rowp + k);
            const float4v u1 = *(const float4v*)(rowp + k + 4);
            half8 v;
#pragma unroll
            for (int e = 0; e < 4; ++e) { v[e] = (_Float16)u0[e]; v[4 + e] = (_Float16)u1[e]; }
            return v;
        };
        const float* r0i = Wih + (size_t)n_0 * HH;
        const float* r1i = Wih + (size_t)n_1 * HH;
        const float* r0h = Whh + (size_t)n_0 * HH;
        const float* r1h = Whh + (size_t)n_1 * HH;
#pragma unroll
        for (int f = 0; f < 8; ++f) {
            const int k = (f << 5) + (quad << 3);
            Bih0[f] = ldfrag(r0i, k);
            Bih1[f] = ldfrag(r1i, k);
            Bhh0[f] = ldfrag(r0h, k);
            Bhh1[f] = ldfrag(r1h, k);
        }
    }
    const float bias0 = bih[n_0] + bhh[n_0];
    const float bias1 = bih[n_1] + bhh[n_1];

    // ---- staging geometry: threads 0..127 own A-frag entry tid:
    // m=tid&3, k0=(tid>>2)*8 (entry index == tid, bijection).
    const int sact = (tid < 128);
    const int cm   = tid & 3;
    const int ck0  = (tid >> 2) << 3;
    const int chc  = c0 + cm;

    // immediate stage (init + non-ws fallback only); sact threads only.
    auto stage_now = [&](int sn) -> half8 {
        const int i = isY ? chc : sn;
        const int j = isY ? sn : ((chc + sn) & 127);
        const size_t cell = (size_t)(b * SS + i) * TT + j;
        half8 v;
        if (DI == 0) {
            const float* row = isY ? (trg + (size_t)(b * TT + j) * HH)
                                   : (src + (size_t)(b * SS + i) * HH);
            const float4v u0 = *(const float4v*)(row + ck0);
            const float4v u1 = *(const float4v*)(row + ck0 + 4);
#pragma unroll
            for (int e = 0; e < 4; ++e) { v[e] = (_Float16)u0[e]; v[4 + e] = (_Float16)u1[e]; }
        } else if (use_ws) {
            v = *(const half8*)(wsg + cell * HH + ck0);
        } else {
            const float* row = out + cell * 2 * HH + (size_t)slot * HH + ck0;
            const float4v u0 = *(const float4v*)(row);
            const float4v u1 = *(const float4v*)(row + 4);
#pragma unroll
            for (int e = 0; e < 4; ++e) { v[e] = (_Float16)u0[e]; v[4 + e] = (_Float16)u1[e]; }
        }
        return v;
    };

    // ---- depth-4 x-prefetch FIFO (sact threads only).
    half8  qh[4];               // DI>0 && use_ws: f16 ws rows
    float4v qa[4], qb[4];       // DI==0: raw f32 (convert at consume)

    auto fifo_issue = [&](int u, int t) {
        const int i = isY ? chc : t;
        const int j = isY ? t : ((chc + t) & 127);
        if constexpr (DI == 0) {
            const float* row = isY ? (trg + (size_t)(b * TT + j) * HH)
                                   : (src + (size_t)(b * SS + i) * HH);
            qa[u] = *(const float4v*)(row + ck0);
            qb[u] = *(const float4v*)(row + ck0 + 4);
        } else {
            if (use_ws) {
                const size_t cell = (size_t)(b * SS + i) * TT + j;
                qh[u] = *(const half8*)(wsg + cell * HH + ck0);
            }
        }
    };

    auto fifo_take = [&](int u, int snext) -> half8 {
        half8 v;
        if constexpr (DI == 0) {
#pragma unroll
            for (int e = 0; e < 4; ++e) { v[e] = (_Float16)qa[u][e]; v[4 + e] = (_Float16)qb[u][e]; }
        } else {
            if (use_ws) {
                v = qh[u];
            } else {
                if (snext > 127) snext = 127;
                v = stage_now(snext);   // slow fallback path only
            }
        }
        return v;
    };

    // ---- h-store from LDS readback (sact threads; 1KB/cell contiguous)
    auto store_h = [&](int sp, int bufi) {
        const half8 v = aH[bufi][tid];
        const int i = isY ? chc : sp;
        const int j = isY ? sp : ((chc + sp) & 127);
        const size_t cell = (size_t)(b * SS + i) * TT + j;
        if (DI == 2 || !use_ws) {
            float* p = out + cell * 2 * HH + (size_t)slot * HH + ck0;
            float4v u0, u1;
#pragma unroll
            for (int e = 0; e < 4; ++e) { u0[e] = (float)v[e]; u1[e] = (float)v[4 + e]; }
            *(float4v*)p = u0;
            *(float4v*)(p + 4) = u1;
        }
        if (DI < 2 && use_ws) {
            *(half8*)(wsg + cell * HH + ck0) = v;
        }
    };

    // ---- init: zero h-state buf 0, stage X(0), prime the FIFO.
    if (sact) {
        half8 z;
#pragma unroll
        for (int e = 0; e < 8; ++e) z[e] = (_Float16)0.f;
        aH[0][tid] = z;
        aX[0][tid] = stage_now(0);
#pragma unroll
        for (int u = 0; u < 4; ++u) fifo_issue(u, u + 1);   // x(1)..x(4)
    }
    __syncthreads();   // one full drain at init only

    const int lrow = lane & 3;     // mirrored A row for this lane

    int buf = 0;
    for (int s4 = 0; s4 < 128; s4 += 4) {
#pragma unroll
        for (int u = 0; u < 4; ++u) {
            const int s = s4 + u;

            // h(s-1) -> global; stores retire lazily (no vmcnt drain at barrier)
            if (s > 0 && sact) store_h(s - 1, buf);

            // x(s+1) -> LDS; its load was issued 4 steps ago
            if (sact) {
                aX[buf ^ 1][tid] = fifo_take(u, s + 1);
                int t = s + 5; if (t > 127) t = 127;
                fifo_issue(u, t);   // refill slot u with x(s+5)
            }

            // A-frags from LDS: entry f*16 + quad*4 + (lane&3).
            // Lanes with (lane&15)>=4 mirror row (lane&3) -> broadcast read.
            half8 axr[8], ahr[8];
#pragma unroll
            for (int f = 0; f < 8; ++f) {
                const int e = (f << 4) + (quad << 2) + lrow;
                axr[f] = aX[buf][e];
                ahr[f] = aH[buf][e];
            }

            // D = Xin@Wih^T + Hprev@Whh^T + bias (4 independent 8-deep chains)
            float4v ax0 = {bias0, bias0, bias0, bias0};
            float4v ax1 = {bias1, bias1, bias1, bias1};
            float4v ah0 = {0.f, 0.f, 0.f, 0.f};
            float4v ah1 = {0.f, 0.f, 0.f, 0.f};
#pragma unroll
            for (int f = 0; f < 8; ++f) {
                ax0 = __builtin_amdgcn_mfma_f32_16x16x32_f16(axr[f], Bih0[f], ax0, 0, 0, 0);
                ax1 = __builtin_amdgcn_mfma_f32_16x16x32_f16(axr[f], Bih1[f], ax1, 0, 0, 0);
                ah0 = __builtin_amdgcn_mfma_f32_16x16x32_f16(ahr[f], Bhh0[f], ah0, 0, 0, 0);
                ah1 = __builtin_amdgcn_mfma_f32_16x16x32_f16(ahr[f], Bhh1[f], ah1, 0, 0, 0);
            }

            // tanh + scatter h(s) into aH[buf^1] — only quad 0 holds rows 0..3
            if (quad == 0) {
                unsigned short* aHu = (unsigned short*)aH[buf ^ 1];
                const int l = lane;            // 0..15
                const int lo3 = l & 7;
                const int hi  = l >> 3;        // 0/1
#pragma unroll
                for (int r = 0; r < 4; ++r) {
                    const float h0 = fast_tanh(ax0[r] + ah0[r]);
                    const float h1 = fast_tanh(ax1[r] + ah1[r]);
                    // tile0: k=32wv+l -> idx=(wv<<7)+((hi)<<5)+(r<<3)+lo3
                    // tile1: k+16     -> idx=(wv<<7)+((2+hi)<<5)+(r<<3)+lo3
                    aHu[(wv << 7) + (hi << 5) + (r << 3) + lo3]       = f2hbits(h0);
                    aHu[(wv << 7) + ((2 + hi) << 5) + (r << 3) + lo3] = f2hbits(h1);
                }
            }

            lds_barrier();   // LDS-only: lgkmcnt(0) + s_barrier, NO vmcnt drain
            buf ^= 1;
        }
    }

    // epilogue: store h(127)
    if (sact) store_h(127, buf);
}

extern "C" __global__ void __launch_bounds__(512, 2)
grid_rnn_d0(const float* __restrict__ src, const float* __restrict__ trg,
            const float* __restrict__ Wx_ih, const float* __restrict__ Wx_hh,
            const float* __restrict__ bx_ih, const float* __restrict__ bx_hh,
            const float* __restrict__ Wy_ih, const float* __restrict__ Wy_hh,
            const float* __restrict__ by_ih, const float* __restrict__ by_hh,
            float* __restrict__ out, unsigned short* __restrict__ ws, int use_ws)
{
    grid_rnn_body<0>(src, trg, Wx_ih, Wx_hh, bx_ih, bx_hh,
                     Wy_ih, Wy_hh, by_ih, by_hh, out, ws, use_ws);
}

extern "C" __global__ void __launch_bounds__(512, 2)
grid_rnn_d1(const float* __restrict__ src, const float* __restrict__ trg,
            const float* __restrict__ Wx_ih, const float* __restrict__ Wx_hh,
            const float* __restrict__ bx_ih, const float* __restrict__ bx_hh,
            const float* __restrict__ Wy_ih, const float* __restrict__ Wy_hh,
            const float* __restrict__ by_ih, const float* __restrict__ by_hh,
            float* __restrict__ out, unsigned short* __restrict__ ws, int use_ws)
{
    grid_rnn_body<1>(src, trg, Wx_ih, Wx_hh, bx_ih, bx_hh,
                     Wy_ih, Wy_hh, by_ih, by_hh, out, ws, use_ws);
}

extern "C" __global__ void __launch_bounds__(512, 2)
grid_rnn_d2(const float* __restrict__ src, const float* __restrict__ trg,
            const float* __restrict__ Wx_ih, const float* __restrict__ Wx_hh,
            const float* __restrict__ bx_ih, const float* __restrict__ bx_hh,
            const float* __restrict__ Wy_ih, const float* __restrict__ Wy_hh,
            const float* __restrict__ by_ih, const float* __restrict__ by_hh,
            float* __restrict__ out, unsigned short* __restrict__ ws, int use_ws)
{
    grid_rnn_body<2>(src, trg, Wx_ih, Wx_hh, bx_ih, bx_hh,
                     Wy_ih, Wy_hh, by_ih, by_hh, out, ws, use_ws);
}

extern "C" void kernel_launch(void* const* d_in, const int* in_sizes, int n_in,
                              void* d_out, int out_size, void* d_ws, size_t ws_size,
                              hipStream_t stream) {
    const float* src   = (const float*)d_in[0];
    const float* trg   = (const float*)d_in[1];
    const float* Wx_ih = (const float*)d_in[2];
    const float* Wx_hh = (const float*)d_in[3];
    const float* bx_ih = (const float*)d_in[4];
    const float* bx_hh = (const float*)d_in[5];
    const float* Wy_ih = (const float*)d_in[6];
    const float* Wy_hh = (const float*)d_in[7];
    const float* by_ih = (const float*)d_in[8];
    const float* by_hh = (const float*)d_in[9];
    float* out = (float*)d_out;
    unsigned short* ws = (unsigned short*)d_ws;

    const size_t need = 2 * GRID_ELEMS * sizeof(unsigned short);  // 67.1 MB
    const int use_ws = (ws_size >= need) ? 1 : 0;

    hipLaunchKernelGGL(grid_rnn_d0, dim3(256), dim3(512), 0, stream,
                       src, trg, Wx_ih, Wx_hh, bx_ih, bx_hh,
                       Wy_ih, Wy_hh, by_ih, by_hh, out, ws, use_ws);
    hipLaunchKernelGGL(grid_rnn_d1, dim3(256), dim3(512), 0, stream,
                       src, trg, Wx_ih, Wx_hh, bx_ih, bx_hh,
                       Wy_ih, Wy_hh, by_ih, by_hh, out, ws, use_ws);
    hipLaunchKernelGGL(grid_rnn_d2, dim3(256), dim3(512), 0, stream,
                       src, trg, Wx_ih, Wx_hh, bx_ih, bx_hh,
                       Wy_ih, Wy_hh, by_ih, by_hh, out, ws, use_ws);
}

// Round 3
// 578.700 us; speedup vs baseline: 1.3585x; 1.1170x over previous
//
#include <hip/hip_runtime.h>

// GridRNN B=4, S=T=128, H=256, D=3 — R8: hoist x@Wih^T out of the recurrence.
//
// Structure (use_ws path):
//   gemm<0>  : P0[dir][b*128+t][n] = x0 @ Wih[0]^T + bih+bhh (compact, x0=src/trg)
//   rnn2<0>  : h = tanh(P + h@Whh^T), h -> ws (f16)
//   gemm<1>  : P[cell][dir][n] = h_prev @ Wih[d]^T + bias  -> out (f32, full grid)
//   rnn2<1>  : h -> ws
//   gemm<1>  : depth 2
//   rnn2<2>  : h -> out (f32), overwriting P cell-by-cell AFTER each cell's P
//              was consumed (P(cell@step t) load issued at t-4; h stored at t+1).
//
// rnn2 per step per wave: 8 ds_read_b128 (aH) + 16 MFMA (K=256) + 8 P-loads
// (4-deep FIFO, f32) + 2 tanh/lane (chain=quad) + scatter + LDS-only barrier.
// MFMA floor: 2 waves/SIMD x 16 x ~19.4cy = 621 cy/step (was 1242).
//
// P stored f32 => numerics identical to R7's split f32 accumulators.

#define SS 128
#define TT 128
#define HH 256
#define GRID_ELEMS ((size_t)4 * 128 * 128 * 256)

typedef _Float16 half8 __attribute__((ext_vector_type(8)));
typedef float float4v __attribute__((ext_vector_type(4)));

__device__ __forceinline__ float fast_tanh(float x) {
    float e = __expf(2.0f * x);
    return 1.0f - 2.0f / (e + 1.0f);
}

__device__ __forceinline__ unsigned short f2hbits(float x) {
    _Float16 h = (_Float16)x;
    return __builtin_bit_cast(unsigned short, h);
}

__device__ __forceinline__ float sel4(float4v v, int q) {
    float a = (q & 1) ? v[1] : v[0];
    float b = (q & 1) ? v[3] : v[2];
    return (q & 2) ? b : a;
}

// LDS-only workgroup barrier: no vmcnt drain (stores retire lazily,
// prefetch loads stay in flight across steps).
__device__ __forceinline__ void lds_barrier() {
    asm volatile("s_waitcnt lgkmcnt(0)" ::: "memory");
    __builtin_amdgcn_s_barrier();
}

__device__ __forceinline__ half8 ldfrag_f32(const float* rowp, int k) {
    const float4v u0 = *(const float4v*)(rowp + k);
    const float4v u1 = *(const float4v*)(rowp + k + 4);
    half8 v;
#pragma unroll
    for (int e = 0; e < 4; ++e) { v[e] = (_Float16)u0[e]; v[4 + e] = (_Float16)u1[e]; }
    return v;
}

// ===================== precompute GEMM =====================
// SRC=0: d0 compact. A rows = src/trg (f32), M=512/dir. Out: P0 compact
//        out[dir*131072 + row*256 + n].
// SRC=1: full-grid. A rows = ws h f16 (65536 cells/dir). Out:
//        out[cell*512 + dir*256 + n]  (f32).
// wg = 512 thr (8 waves), M-tile = 64 rows, N = 256 (wave wv: n0=32*wv).
template <int SRC>
__device__ __forceinline__ void gemm_body(
    const float* __restrict__ src, const float* __restrict__ trg,
    const float* __restrict__ Wx_ih, const float* __restrict__ Wy_ih,
    const float* __restrict__ bx_ih, const float* __restrict__ bx_hh,
    const float* __restrict__ by_ih, const float* __restrict__ by_hh,
    const unsigned short* __restrict__ ws, float* __restrict__ out, int d)
{
    __shared__ half8 aT[2048];   // 64 rows x 256 k, frag layout, 32 KB

    const int tid  = threadIdx.x;
    const int lane = tid & 63;
    const int wv   = tid >> 6;
    const int quad = lane >> 4;
    const int l15  = lane & 15;

    const int bx   = blockIdx.x;
    const int dir   = (SRC == 0) ? (bx >> 3) : (bx >> 10);
    const int mtile = (SRC == 0) ? (bx & 7)  : (bx & 1023);

    const float* Wih = (dir ? Wy_ih : Wx_ih) + (size_t)d * HH * HH;
    const float* bih = (dir ? by_ih : bx_ih) + d * HH;
    const float* bhh = (dir ? by_hh : bx_hh) + d * HH;

    const int n_0 = (wv << 5) + l15;
    const int n_1 = n_0 + 16;

    half8 B0[8], B1[8];
    {
        const float* r0 = Wih + (size_t)n_0 * HH;
        const float* r1 = Wih + (size_t)n_1 * HH;
#pragma unroll
        for (int f = 0; f < 8; ++f) {
            const int k = (f << 5) + (quad << 3);
            B0[f] = ldfrag_f32(r0, k);
            B1[f] = ldfrag_f32(r1, k);
        }
    }
    const float bias0 = bih[n_0] + bhh[n_0];
    const float bias1 = bih[n_1] + bhh[n_1];

    // stage A tile: 2048 chunks of 8 f16; thread t owns chunks 4t..4t+3
#pragma unroll
    for (int i = 0; i < 4; ++i) {
        const int c  = (tid << 2) + i;
        const int r  = c >> 5;      // row in tile 0..63
        const int kc = c & 31;      // k-chunk 0..31
        half8 v;
        if constexpr (SRC == 0) {
            const int R = (mtile << 6) + r;           // 0..511
            const int b = R >> 7, ii = R & 127;
            const float* row = (dir ? trg : src) + (size_t)((b << 7) + ii) * HH + (kc << 3);
            const float4v u0 = *(const float4v*)(row);
            const float4v u1 = *(const float4v*)(row + 4);
#pragma unroll
            for (int e = 0; e < 4; ++e) { v[e] = (_Float16)u0[e]; v[4 + e] = (_Float16)u1[e]; }
        } else {
            const unsigned short* wsg = ws + (size_t)dir * GRID_ELEMS;
            const size_t cell = (size_t)(mtile << 6) + r;
            v = *(const half8*)(wsg + cell * HH + (kc << 3));
        }
        aT[((r >> 4) << 9) + ((kc >> 2) << 6) + ((kc & 3) << 4) + (r & 15)] = v;
    }
    __syncthreads();

#pragma unroll
    for (int msub = 0; msub < 4; ++msub) {
        half8 af[8];
#pragma unroll
        for (int f = 0; f < 8; ++f)
            af[f] = aT[(msub << 9) + (f << 6) + (quad << 4) + l15];

        float4v c0 = {bias0, bias0, bias0, bias0};
        float4v c1 = {bias1, bias1, bias1, bias1};
#pragma unroll
        for (int f = 0; f < 8; ++f) {
            c0 = __builtin_amdgcn_mfma_f32_16x16x32_f16(af[f], B0[f], c0, 0, 0, 0);
            c1 = __builtin_amdgcn_mfma_f32_16x16x32_f16(af[f], B1[f], c1, 0, 0, 0);
        }
#pragma unroll
        for (int r = 0; r < 4; ++r) {
            const int row = (msub << 4) + (quad << 2) + r;
            if constexpr (SRC == 0) {
                float* p = out + (size_t)dir * 131072 + (size_t)((mtile << 6) + row) * HH;
                p[n_0] = c0[r];
                p[n_1] = c1[r];
            } else {
                const size_t cell = (size_t)(mtile << 6) + row;
                float* p = out + cell * 2 * HH + (size_t)dir * HH;
                p[n_0] = c0[r];
                p[n_1] = c1[r];
            }
        }
    }
}

extern "C" __global__ void __launch_bounds__(512, 2)
grid_gemm0(const float* __restrict__ src, const float* __restrict__ trg,
           const float* __restrict__ Wx_ih, const float* __restrict__ Wy_ih,
           const float* __restrict__ bx_ih, const float* __restrict__ bx_hh,
           const float* __restrict__ by_ih, const float* __restrict__ by_hh,
           const unsigned short* __restrict__ ws, float* __restrict__ out, int d)
{ gemm_body<0>(src, trg, Wx_ih, Wy_ih, bx_ih, bx_hh, by_ih, by_hh, ws, out, d); }

extern "C" __global__ void __launch_bounds__(512, 2)
grid_gemm1(const float* __restrict__ src, const float* __restrict__ trg,
           const float* __restrict__ Wx_ih, const float* __restrict__ Wy_ih,
           const float* __restrict__ bx_ih, const float* __restrict__ bx_hh,
           const float* __restrict__ by_ih, const float* __restrict__ by_hh,
           const unsigned short* __restrict__ ws, float* __restrict__ out, int d)
{ gemm_body<1>(src, trg, Wx_ih, Wy_ih, bx_ih, bx_hh, by_ih, by_hh, ws, out, d); }

// ===================== recurrence kernel (MODE2) =====================
// h = tanh(P + h_prev @ Whh^T); P prefetched 4 steps deep from `out`.
template <int DI>
__device__ __forceinline__ void rnn2_body(
    const float* __restrict__ Wx_hh, const float* __restrict__ Wy_hh,
    float* __restrict__ out, unsigned short* __restrict__ ws)
{
    __shared__ half8 aH[2][128];   // 4 rows x 256 k, frag layout, dbuf

    const int tid  = threadIdx.x;
    const int lane = tid & 63;
    const int wv   = tid >> 6;
    const int quad = lane >> 4;
    const int l15  = lane & 15;
    const int lrow = lane & 3;

    const int bid  = blockIdx.x;   // 0..255
    const int isY  = bid >= 128;
    const int g    = isY ? bid - 128 : bid;
    const int b    = g >> 5;
    const int c0   = (g & 31) << 2;
    const int slot = isY;

    const float* Whh = (isY ? Wy_hh : Wx_hh) + (size_t)DI * HH * HH;
    unsigned short* wsg = ws + (size_t)isY * GRID_ELEMS;

    const int n_0 = (wv << 5) + l15;
    const int n_1 = n_0 + 16;

    half8 Bhh0[8], Bhh1[8];
    {
        const float* r0 = Whh + (size_t)n_0 * HH;
        const float* r1 = Whh + (size_t)n_1 * HH;
#pragma unroll
        for (int f = 0; f < 8; ++f) {
            const int k = (f << 5) + (quad << 3);
            Bhh0[f] = ldfrag_f32(r0, k);
            Bhh1[f] = ldfrag_f32(r1, k);
        }
    }

    // staging geometry (threads 0..127 own aH entry tid: m=tid&3, k0=(tid>>2)*8)
    const int sact = (tid < 128);
    const int cm   = tid & 3;
    const int ck0  = (tid >> 2) << 3;
    const int chc  = c0 + cm;

    auto store_h = [&](int sp, int bufi) {
        const half8 v = aH[bufi][tid];
        const int i = isY ? chc : sp;
        const int j = isY ? sp : ((chc + sp) & 127);
        const size_t cell = (size_t)(b * SS + i) * TT + j;
        if constexpr (DI == 2) {
            float* p = out + cell * 2 * HH + (size_t)slot * HH + ck0;
            float4v u0, u1;
#pragma unroll
            for (int e = 0; e < 4; ++e) { u0[e] = (float)v[e]; u1[e] = (float)v[4 + e]; }
            *(float4v*)p = u0;
            *(float4v*)(p + 4) = u1;
        } else {
            *(half8*)(wsg + cell * HH + ck0) = v;
        }
    };

    // ---- P prefetch FIFO (depth 4). Slot u holds P(s) for s≡u (mod 4).
    float fA[4][4], fB[4][4];   // DI>0: per-chain P values (tile0/tile1)
    float gA[4],    gB[4];      // DI==0: compact (chain-independent)

    auto fifo_issue = [&](int u, int t) {
        if constexpr (DI == 0) {
            const float* p = out + (size_t)isY * 131072 + (size_t)((b << 7) + t) * HH;
            gA[u] = p[n_0];
            gB[u] = p[n_1];
        } else {
#pragma unroll
            for (int r = 0; r < 4; ++r) {
                const int i = isY ? (c0 + r) : t;
                const int j = isY ? t : ((c0 + r + t) & 127);
                const float* p = out + ((size_t)(b * SS + i) * TT + j) * 2 * HH + (size_t)slot * HH;
                fA[u][r] = p[n_0];
                fB[u][r] = p[n_1];
            }
        }
    };

    // ---- init: zero h-state buf 0; prime FIFO with P(0..3).
    if (sact) {
        half8 z;
#pragma unroll
        for (int e = 0; e < 8; ++e) z[e] = (_Float16)0.f;
        aH[0][tid] = z;
    }
#pragma unroll
    for (int u = 0; u < 4; ++u) fifo_issue(u, u);
    __syncthreads();

    const int hi  = l15 >> 3;
    const int lo3 = l15 & 7;

    int buf = 0;
    for (int s4 = 0; s4 < 128; s4 += 4) {
#pragma unroll
        for (int u = 0; u < 4; ++u) {
            const int s = s4 + u;

            // h(s-1) -> global; retires lazily
            if (s > 0 && sact) store_h(s - 1, buf);

            // acc init from FIFO slot u = P(s)
            float4v ah0, ah1;
            if constexpr (DI == 0) {
                const float pa = gA[u], pb = gB[u];
                ah0 = float4v{pa, pa, pa, pa};
                ah1 = float4v{pb, pb, pb, pb};
            } else {
#pragma unroll
                for (int r = 0; r < 4; ++r) { ah0[r] = fA[u][r]; ah1[r] = fB[u][r]; }
            }

            // refill slot u with P(s+4) (clamped; tail loads never consumed)
            {
                int t = s + 4; if (t > 127) t = 127;
                fifo_issue(u, t);
            }

            // A-frags: entry f*16 + quad*4 + (lane&3); rows mirror mod 4
            half8 ahr[8];
#pragma unroll
            for (int f = 0; f < 8; ++f)
                ahr[f] = aH[buf][(f << 4) + (quad << 2) + lrow];

#pragma unroll
            for (int f = 0; f < 8; ++f) {
                ah0 = __builtin_amdgcn_mfma_f32_16x16x32_f16(ahr[f], Bhh0[f], ah0, 0, 0, 0);
                ah1 = __builtin_amdgcn_mfma_f32_16x16x32_f16(ahr[f], Bhh1[f], ah1, 0, 0, 0);
            }

            // tanh + scatter: each lane handles chain r = quad (2 values)
            const float h0 = fast_tanh(sel4(ah0, quad));
            const float h1 = fast_tanh(sel4(ah1, quad));
            unsigned short* aHu = (unsigned short*)aH[buf ^ 1];
            aHu[(((wv << 4) + (hi << 2) + quad) << 3) + lo3]       = f2hbits(h0);
            aHu[(((wv << 4) + ((2 + hi) << 2) + quad) << 3) + lo3] = f2hbits(h1);

            lds_barrier();   // LDS-only barrier
            buf ^= 1;
        }
    }

    if (sact) store_h(127, buf);
}

extern "C" __global__ void __launch_bounds__(512, 2)
grid_rnn2_d0(const float* __restrict__ Wx_hh, const float* __restrict__ Wy_hh,
             float* __restrict__ out, unsigned short* __restrict__ ws)
{ rnn2_body<0>(Wx_hh, Wy_hh, out, ws); }

extern "C" __global__ void __launch_bounds__(512, 2)
grid_rnn2_d1(const float* __restrict__ Wx_hh, const float* __restrict__ Wy_hh,
             float* __restrict__ out, unsigned short* __restrict__ ws)
{ rnn2_body<1>(Wx_hh, Wy_hh, out, ws); }

extern "C" __global__ void __launch_bounds__(512, 2)
grid_rnn2_d2(const float* __restrict__ Wx_hh, const float* __restrict__ Wy_hh,
             float* __restrict__ out, unsigned short* __restrict__ ws)
{ rnn2_body<2>(Wx_hh, Wy_hh, out, ws); }

// ===================== R7 fallback (no workspace) =====================
template <int DI>
__device__ __forceinline__ void grid_rnn_body_v1(
    const float* __restrict__ src, const float* __restrict__ trg,
    const float* __restrict__ Wx_ih, const float* __restrict__ Wx_hh,
    const float* __restrict__ bx_ih, const float* __restrict__ bx_hh,
    const float* __restrict__ Wy_ih, const float* __restrict__ Wy_hh,
    const float* __restrict__ by_ih, const float* __restrict__ by_hh,
    float* __restrict__ out)
{
    __shared__ half8 aX[2][128];
    __shared__ half8 aH[2][128];

    const int tid  = threadIdx.x;
    const int lane = tid & 63;
    const int wv   = tid >> 6;
    const int quad = lane >> 4;
    const int l15  = lane & 15;

    const int bid  = blockIdx.x;
    const int isY  = bid >= 128;
    const int g    = isY ? bid - 128 : bid;
    const int b    = g >> 5;
    const int c0   = (g & 31) << 2;
    const int slot = isY;

    const float* Wih = (isY ? Wy_ih : Wx_ih) + (size_t)DI * HH * HH;
    const float* Whh = (isY ? Wy_hh : Wx_hh) + (size_t)DI * HH * HH;
    const float* bih = (isY ? by_ih : bx_ih) + DI * HH;
    const float* bhh = (isY ? by_hh : bx_hh) + DI * HH;

    const int n_0 = (wv << 5) + l15;
    const int n_1 = n_0 + 16;

    half8 Bih0[8], Bih1[8], Bhh0[8], Bhh1[8];
    {
        const float* r0i = Wih + (size_t)n_0 * HH;
        const float* r1i = Wih + (size_t)n_1 * HH;
        const float* r0h = Whh + (size_t)n_0 * HH;
        const float* r1h = Whh + (size_t)n_1 * HH;
#pragma unroll
        for (int f = 0; f < 8; ++f) {
            const int k = (f << 5) + (quad << 3);
            Bih0[f] = ldfrag_f32(r0i, k);
            Bih1[f] = ldfrag_f32(r1i, k);
            Bhh0[f] = ldfrag_f32(r0h, k);
            Bhh1[f] = ldfrag_f32(r1h, k);
        }
    }
    const float bias0 = bih[n_0] + bhh[n_0];
    const float bias1 = bih[n_1] + bhh[n_1];

    const int sact = (tid < 128);
    const int cm   = tid & 3;
    const int ck0  = (tid >> 2) << 3;
    const int chc  = c0 + cm;

    auto stage_now = [&](int sn) -> half8 {
        const int i = isY ? chc : sn;
        const int j = isY ? sn : ((chc + sn) & 127);
        const size_t cell = (size_t)(b * SS + i) * TT + j;
        half8 v;
        if constexpr (DI == 0) {
            const float* row = isY ? (trg + (size_t)(b * TT + j) * HH)
                                   : (src + (size_t)(b * SS + i) * HH);
            const float4v u0 = *(const float4v*)(row + ck0);
            const float4v u1 = *(const float4v*)(row + ck0 + 4);
#pragma unroll
            for (int e = 0; e < 4; ++e) { v[e] = (_Float16)u0[e]; v[4 + e] = (_Float16)u1[e]; }
        } else {
            const float* row = out + cell * 2 * HH + (size_t)slot * HH + ck0;
            const float4v u0 = *(const float4v*)(row);
            const float4v u1 = *(const float4v*)(row + 4);
#pragma unroll
            for (int e = 0; e < 4; ++e) { v[e] = (_Float16)u0[e]; v[4 + e] = (_Float16)u1[e]; }
        }
        return v;
    };

    auto store_h = [&](int sp, int bufi) {
        const half8 v = aH[bufi][tid];
        const int i = isY ? chc : sp;
        const int j = isY ? sp : ((chc + sp) & 127);
        const size_t cell = (size_t)(b * SS + i) * TT + j;
        float* p = out + cell * 2 * HH + (size_t)slot * HH + ck0;
        float4v u0, u1;
#pragma unroll
        for (int e = 0; e < 4; ++e) { u0[e] = (float)v[e]; u1[e] = (float)v[4 + e]; }
        *(float4v*)p = u0;
        *(float4v*)(p + 4) = u1;
    };

    if (sact) {
        half8 z;
#pragma unroll
        for (int e = 0; e < 8; ++e) z[e] = (_Float16)0.f;
        aH[0][tid] = z;
        aX[0][tid] = stage_now(0);
    }
    __syncthreads();

    const int lrow = lane & 3;

    int buf = 0;
    for (int s = 0; s < 128; ++s) {
        if (s > 0 && sact) store_h(s - 1, buf);
        if (sact) {
            int t = s + 1; if (t > 127) t = 127;
            aX[buf ^ 1][tid] = stage_now(t);
        }

        half8 axr[8], ahr[8];
#pragma unroll
        for (int f = 0; f < 8; ++f) {
            const int e = (f << 4) + (quad << 2) + lrow;
            axr[f] = aX[buf][e];
            ahr[f] = aH[buf][e];
        }

        float4v ax0 = {bias0, bias0, bias0, bias0};
        float4v ax1 = {bias1, bias1, bias1, bias1};
        float4v ah0 = {0.f, 0.f, 0.f, 0.f};
        float4v ah1 = {0.f, 0.f, 0.f, 0.f};
#pragma unroll
        for (int f = 0; f < 8; ++f) {
            ax0 = __builtin_amdgcn_mfma_f32_16x16x32_f16(axr[f], Bih0[f], ax0, 0, 0, 0);
            ax1 = __builtin_amdgcn_mfma_f32_16x16x32_f16(axr[f], Bih1[f], ax1, 0, 0, 0);
            ah0 = __builtin_amdgcn_mfma_f32_16x16x32_f16(ahr[f], Bhh0[f], ah0, 0, 0, 0);
            ah1 = __builtin_amdgcn_mfma_f32_16x16x32_f16(ahr[f], Bhh1[f], ah1, 0, 0, 0);
        }

        if (quad == 0) {
            unsigned short* aHu = (unsigned short*)aH[buf ^ 1];
            const int lo3 = lane & 7;
            const int hi  = lane >> 3;
#pragma unroll
            for (int r = 0; r < 4; ++r) {
                const float h0 = fast_tanh(ax0[r] + ah0[r]);
                const float h1 = fast_tanh(ax1[r] + ah1[r]);
                aHu[(wv << 7) + (hi << 5) + (r << 3) + lo3]       = f2hbits(h0);
                aHu[(wv << 7) + ((2 + hi) << 5) + (r << 3) + lo3] = f2hbits(h1);
            }
        }

        lds_barrier();
        buf ^= 1;
    }

    if (sact) store_h(127, buf);
}

extern "C" __global__ void __launch_bounds__(512, 2)
grid_rnn_v1_d0(const float* __restrict__ src, const float* __restrict__ trg,
               const float* __restrict__ Wx_ih, const float* __restrict__ Wx_hh,
               const float* __restrict__ bx_ih, const float* __restrict__ bx_hh,
               const float* __restrict__ Wy_ih, const float* __restrict__ Wy_hh,
               const float* __restrict__ by_ih, const float* __restrict__ by_hh,
               float* __restrict__ out)
{ grid_rnn_body_v1<0>(src, trg, Wx_ih, Wx_hh, bx_ih, bx_hh, Wy_ih, Wy_hh, by_ih, by_hh, out); }

extern "C" __global__ void __launch_bounds__(512, 2)
grid_rnn_v1_d1(const float* __restrict__ src, const float* __restrict__ trg,
               const float* __restrict__ Wx_ih, const float* __restrict__ Wx_hh,
               const float* __restrict__ bx_ih, const float* __restrict__ bx_hh,
               const float* __restrict__ Wy_ih, const float* __restrict__ Wy_hh,
               const float* __restrict__ by_ih, const float* __restrict__ by_hh,
               float* __restrict__ out)
{ grid_rnn_body_v1<1>(src, trg, Wx_ih, Wx_hh, bx_ih, bx_hh, Wy_ih, Wy_hh, by_ih, by_hh, out); }

extern "C" __global__ void __launch_bounds__(512, 2)
grid_rnn_v1_d2(const float* __restrict__ src, const float* __restrict__ trg,
               const float* __restrict__ Wx_ih, const float* __restrict__ Wx_hh,
               const float* __restrict__ bx_ih, const float* __restrict__ bx_hh,
               const float* __restrict__ Wy_ih, const float* __restrict__ Wy_hh,
               const float* __restrict__ by_ih, const float* __restrict__ by_hh,
               float* __restrict__ out)
{ grid_rnn_body_v1<2>(src, trg, Wx_ih, Wx_hh, bx_ih, bx_hh, Wy_ih, Wy_hh, by_ih, by_hh, out); }

// ===================== launch =====================
extern "C" void kernel_launch(void* const* d_in, const int* in_sizes, int n_in,
                              void* d_out, int out_size, void* d_ws, size_t ws_size,
                              hipStream_t stream) {
    const float* src   = (const float*)d_in[0];
    const float* trg   = (const float*)d_in[1];
    const float* Wx_ih = (const float*)d_in[2];
    const float* Wx_hh = (const float*)d_in[3];
    const float* bx_ih = (const float*)d_in[4];
    const float* bx_hh = (const float*)d_in[5];
    const float* Wy_ih = (const float*)d_in[6];
    const float* Wy_hh = (const float*)d_in[7];
    const float* by_ih = (const float*)d_in[8];
    const float* by_hh = (const float*)d_in[9];
    float* out = (float*)d_out;
    unsigned short* ws = (unsigned short*)d_ws;

    const size_t need = 2 * GRID_ELEMS * sizeof(unsigned short);  // 67.1 MB
    const int use_ws = (ws_size >= need) ? 1 : 0;

    if (use_ws) {
        // d0: compact P (x depends only on step index), then recurrence
        hipLaunchKernelGGL(grid_gemm0, dim3(16), dim3(512), 0, stream,
                           src, trg, Wx_ih, Wy_ih, bx_ih, bx_hh, by_ih, by_hh,
                           (const unsigned short*)ws, out, 0);
        hipLaunchKernelGGL(grid_rnn2_d0, dim3(256), dim3(512), 0, stream,
                           Wx_hh, Wy_hh, out, ws);
        // d1
        hipLaunchKernelGGL(grid_gemm1, dim3(2048), dim3(512), 0, stream,
                           src, trg, Wx_ih, Wy_ih, bx_ih, bx_hh, by_ih, by_hh,
                           (const unsigned short*)ws, out, 1);
        hipLaunchKernelGGL(grid_rnn2_d1, dim3(256), dim3(512), 0, stream,
                           Wx_hh, Wy_hh, out, ws);
        // d2
        hipLaunchKernelGGL(grid_gemm1, dim3(2048), dim3(512), 0, stream,
                           src, trg, Wx_ih, Wy_ih, bx_ih, bx_hh, by_ih, by_hh,
                           (const unsigned short*)ws, out, 2);
        hipLaunchKernelGGL(grid_rnn2_d2, dim3(256), dim3(512), 0, stream,
                           Wx_hh, Wy_hh, out, ws);
    } else {
        hipLaunchKernelGGL(grid_rnn_v1_d0, dim3(256), dim3(512), 0, stream,
                           src, trg, Wx_ih, Wx_hh, bx_ih, bx_hh,
                           Wy_ih, Wy_hh, by_ih, by_hh, out);
        hipLaunchKernelGGL(grid_rnn_v1_d1, dim3(256), dim3(512), 0, stream,
                           src, trg, Wx_ih, Wx_hh, bx_ih, bx_hh,
                           Wy_ih, Wy_hh, by_ih, by_hh, out);
        hipLaunchKernelGGL(grid_rnn_v1_d2, dim3(256), dim3(512), 0, stream,
                           src, trg, Wx_ih, Wx_hh, bx_ih, bx_hh,
                           Wy_ih, Wy_hh, by_ih, by_hh, out);
    }
}

// Round 4
// 465.407 us; speedup vs baseline: 1.6891x; 1.2434x over previous
//
#include <hip/hip_runtime.h>

// GridRNN B=4, S=T=128, H=256, D=3 — R9: fuse next-depth ih-GEMM into the
// recurrence; 2-scalar P FIFO (post-add, not acc-init); spread final store.
//
// Pipeline (ws >= 1MB path; ws holds only compact P0, f32, 1 MB):
//   gemm0      : P0[dir][b*128+t][n] = x0 @ Wih[0]^T + bih0+bhh0 -> ws
//   rnn2f<0>   : h=tanh(P0 + h@Whh[0]^T); SAME ahr frags x Wih[1] -> P1 -> out
//   rnn2f<1>   : h=tanh(P1 + h@Whh[1]^T); ahr x Wih[2] -> P2 -> out (per-cell
//                overwrite AFTER consumption: read t-4, write t-1 at step t)
//   rnn2_last  : h=tanh(P2 + h@Whh[2]^T); h -> out f32 (spread 512-thr store)
//
// Key facts used:
//  - MFMA rows mirror mod 4 (A rows 4q+r duplicate r) => acc reg r == chain r
//    for EVERY quad; lane only consumes reg r=quad => P post-add needs only
//    2 scalars/lane (chain=quad), and P-store is 2 dwords/lane (chain=quad).
//  - ih-GEMM reuses the hh ds_reads: +16 MFMA/wave/step, zero LDS traffic.
//  - LDS-only barrier (lgkmcnt+s_barrier): stores retire lazily, FIFO loads
//    stay in flight across steps.

#define SS 128
#define TT 128
#define HH 256
#define GRID_ELEMS ((size_t)4 * 128 * 128 * 256)

typedef _Float16 half8 __attribute__((ext_vector_type(8)));
typedef float float4v __attribute__((ext_vector_type(4)));
typedef float float2v __attribute__((ext_vector_type(2)));

__device__ __forceinline__ float fast_tanh(float x) {
    float e = __expf(2.0f * x);
    return 1.0f - 2.0f / (e + 1.0f);
}

__device__ __forceinline__ unsigned short f2hbits(float x) {
    _Float16 h = (_Float16)x;
    return __builtin_bit_cast(unsigned short, h);
}

__device__ __forceinline__ float sel4(float4v v, int q) {
    float a = (q & 1) ? v[1] : v[0];
    float b = (q & 1) ? v[3] : v[2];
    return (q & 2) ? b : a;
}

__device__ __forceinline__ void lds_barrier() {
    asm volatile("s_waitcnt lgkmcnt(0)" ::: "memory");
    __builtin_amdgcn_s_barrier();
}

__device__ __forceinline__ half8 ldfrag_f32(const float* rowp, int k) {
    const float4v u0 = *(const float4v*)(rowp + k);
    const float4v u1 = *(const float4v*)(rowp + k + 4);
    half8 v;
#pragma unroll
    for (int e = 0; e < 4; ++e) { v[e] = (_Float16)u0[e]; v[4 + e] = (_Float16)u1[e]; }
    return v;
}

// ===================== gemm0: compact P0 -> ws =====================
extern "C" __global__ void __launch_bounds__(512, 2)
grid_gemm0(const float* __restrict__ src, const float* __restrict__ trg,
           const float* __restrict__ Wx_ih, const float* __restrict__ Wy_ih,
           const float* __restrict__ bx_ih, const float* __restrict__ bx_hh,
           const float* __restrict__ by_ih, const float* __restrict__ by_hh,
           float* __restrict__ P0)
{
    __shared__ half8 aT[2048];   // 64 rows x 256 k

    const int tid  = threadIdx.x;
    const int lane = tid & 63;
    const int wv   = tid >> 6;
    const int quad = lane >> 4;
    const int l15  = lane & 15;

    const int bx    = blockIdx.x;   // 0..15
    const int dir   = bx >> 3;
    const int mtile = bx & 7;

    const float* Wih = dir ? Wy_ih : Wx_ih;   // depth 0
    const float* bih = dir ? by_ih : bx_ih;
    const float* bhh = dir ? by_hh : bx_hh;

    const int n_0 = (wv << 5) + l15;
    const int n_1 = n_0 + 16;

    half8 B0[8], B1[8];
    {
        const float* r0 = Wih + (size_t)n_0 * HH;
        const float* r1 = Wih + (size_t)n_1 * HH;
#pragma unroll
        for (int f = 0; f < 8; ++f) {
            const int k = (f << 5) + (quad << 3);
            B0[f] = ldfrag_f32(r0, k);
            B1[f] = ldfrag_f32(r1, k);
        }
    }
    const float bias0 = bih[n_0] + bhh[n_0];
    const float bias1 = bih[n_1] + bhh[n_1];

#pragma unroll
    for (int i = 0; i < 4; ++i) {
        const int c  = (tid << 2) + i;
        const int r  = c >> 5;
        const int kc = c & 31;
        const int R  = (mtile << 6) + r;
        const int b  = R >> 7, ii = R & 127;
        const float* row = (dir ? trg : src) + (size_t)((b << 7) + ii) * HH + (kc << 3);
        const float4v u0 = *(const float4v*)(row);
        const float4v u1 = *(const float4v*)(row + 4);
        half8 v;
#pragma unroll
        for (int e = 0; e < 4; ++e) { v[e] = (_Float16)u0[e]; v[4 + e] = (_Float16)u1[e]; }
        aT[((r >> 4) << 9) + ((kc >> 2) << 6) + ((kc & 3) << 4) + (r & 15)] = v;
    }
    __syncthreads();

#pragma unroll
    for (int msub = 0; msub < 4; ++msub) {
        half8 af[8];
#pragma unroll
        for (int f = 0; f < 8; ++f)
            af[f] = aT[(msub << 9) + (f << 6) + (quad << 4) + l15];

        float4v c0 = {bias0, bias0, bias0, bias0};
        float4v c1 = {bias1, bias1, bias1, bias1};
#pragma unroll
        for (int f = 0; f < 8; ++f) {
            c0 = __builtin_amdgcn_mfma_f32_16x16x32_f16(af[f], B0[f], c0, 0, 0, 0);
            c1 = __builtin_amdgcn_mfma_f32_16x16x32_f16(af[f], B1[f], c1, 0, 0, 0);
        }
#pragma unroll
        for (int r = 0; r < 4; ++r) {
            const int row = (msub << 4) + (quad << 2) + r;
            float* p = P0 + (size_t)dir * 131072 + (size_t)((mtile << 6) + row) * HH;
            p[n_0] = c0[r];
            p[n_1] = c1[r];
        }
    }
}

// ===================== fused recurrence (depths 0,1) =====================
template <int DI>
__device__ __forceinline__ void rnn2f_body(
    const float* __restrict__ Wx_hh, const float* __restrict__ Wy_hh,
    const float* __restrict__ Wx_ih, const float* __restrict__ Wy_ih,
    const float* __restrict__ bx_ih, const float* __restrict__ bx_hh,
    const float* __restrict__ by_ih, const float* __restrict__ by_hh,
    float* __restrict__ out, const float* __restrict__ P0)
{
    __shared__ half8 aH[2][128];

    const int tid  = threadIdx.x;
    const int lane = tid & 63;
    const int wv   = tid >> 6;
    const int quad = lane >> 4;
    const int l15  = lane & 15;
    const int lrow = lane & 3;

    const int bid  = blockIdx.x;   // 0..255
    const int isY  = bid >= 128;
    const int g    = isY ? bid - 128 : bid;
    const int b    = g >> 5;
    const int c0   = (g & 31) << 2;
    const int slot = isY;

    const float* Whh  = (isY ? Wy_hh : Wx_hh) + (size_t)DI * HH * HH;
    const float* WihN = (isY ? Wy_ih : Wx_ih) + (size_t)(DI + 1) * HH * HH;
    const float* bihN = (isY ? by_ih : bx_ih) + (DI + 1) * HH;
    const float* bhhN = (isY ? by_hh : bx_hh) + (DI + 1) * HH;

    const int n_0 = (wv << 5) + l15;
    const int n_1 = n_0 + 16;

    half8 Bhh0[8], Bhh1[8], BN0[8], BN1[8];
    {
        const float* h0p = Whh  + (size_t)n_0 * HH;
        const float* h1p = Whh  + (size_t)n_1 * HH;
        const float* i0p = WihN + (size_t)n_0 * HH;
        const float* i1p = WihN + (size_t)n_1 * HH;
#pragma unroll
        for (int f = 0; f < 8; ++f) {
            const int k = (f << 5) + (quad << 3);
            Bhh0[f] = ldfrag_f32(h0p, k);
            Bhh1[f] = ldfrag_f32(h1p, k);
            BN0[f]  = ldfrag_f32(i0p, k);
            BN1[f]  = ldfrag_f32(i1p, k);
        }
    }
    const float biasN0 = bihN[n_0] + bhhN[n_0];
    const float biasN1 = bihN[n_1] + bhhN[n_1];

    // ---- P_next write pointer (chain = quad), bumped per stored cell
    int wj = isY ? 0 : ((c0 + quad) & 127);
    float* wp = out + (isY ? ((size_t)(b * SS + c0 + quad) * TT)
                           : ((size_t)b * SS * TT + wj)) * 2 * HH
                    + (size_t)slot * HH;

    // ---- P read FIFO (2 scalars/step)
    float pA[4], pB[4];
    int rj = isY ? 0 : ((c0 + quad) & 127);
    const float* rp;
    if constexpr (DI == 0) {
        rp = P0 + (size_t)isY * 131072 + (size_t)b * 128 * HH;
    } else {
        rp = out + (isY ? ((size_t)(b * SS + c0 + quad) * TT)
                        : ((size_t)b * SS * TT + rj)) * 2 * HH
                 + (size_t)slot * HH;
    }
    auto rbump = [&]() {
        if constexpr (DI == 0) { rp += HH; }
        else if (isY)          { rp += 2 * HH; }
        else { rp += (size_t)(rj == 127 ? 1 : 129) * 2 * HH; rj = (rj + 1) & 127; }
    };
#pragma unroll
    for (int u = 0; u < 4; ++u) { pA[u] = rp[n_0]; pB[u] = rp[n_1]; rbump(); }

    if (tid < 128) {
        half8 z;
#pragma unroll
        for (int e = 0; e < 8; ++e) z[e] = (_Float16)0.f;
        aH[0][tid] = z;
    }
    __syncthreads();

    const int hi  = l15 >> 3;
    const int lo3 = l15 & 7;

    int buf = 0;
    for (int s4 = 0; s4 < 128; s4 += 4) {
#pragma unroll
        for (int u = 0; u < 4; ++u) {
            const int s = s4 + u;

            // A-frags (h(s-1)); rows mirror mod 4 (broadcast reads)
            half8 ahr[8];
#pragma unroll
            for (int f = 0; f < 8; ++f)
                ahr[f] = aH[buf][(f << 4) + (quad << 2) + lrow];

            float4v ah0 = {0.f, 0.f, 0.f, 0.f};
            float4v ah1 = {0.f, 0.f, 0.f, 0.f};
            float4v pn0 = {biasN0, biasN0, biasN0, biasN0};
            float4v pn1 = {biasN1, biasN1, biasN1, biasN1};
            __builtin_amdgcn_s_setprio(1);
#pragma unroll
            for (int f = 0; f < 8; ++f) {
                ah0 = __builtin_amdgcn_mfma_f32_16x16x32_f16(ahr[f], Bhh0[f], ah0, 0, 0, 0);
                ah1 = __builtin_amdgcn_mfma_f32_16x16x32_f16(ahr[f], Bhh1[f], ah1, 0, 0, 0);
                pn0 = __builtin_amdgcn_mfma_f32_16x16x32_f16(ahr[f], BN0[f], pn0, 0, 0, 0);
                pn1 = __builtin_amdgcn_mfma_f32_16x16x32_f16(ahr[f], BN1[f], pn1, 0, 0, 0);
            }
            __builtin_amdgcn_s_setprio(0);

            // P_next(cell(s-1)) -> out (lane stores chain=quad at n_0,n_1)
            if (s > 0) {
                wp[n_0] = sel4(pn0, quad);
                wp[n_1] = sel4(pn1, quad);
                if (isY) { wp += 2 * HH; }
                else { wp += (size_t)(wj == 127 ? 1 : 129) * 2 * HH; wj = (wj + 1) & 127; }
            }

            // h(s) = tanh(hh + P(s)); scatter to aH[buf^1]
            const float h0 = fast_tanh(sel4(ah0, quad) + pA[u]);
            const float h1 = fast_tanh(sel4(ah1, quad) + pB[u]);
            unsigned short* aHu = (unsigned short*)aH[buf ^ 1];
            aHu[(((wv << 4) + (hi << 2) + quad) << 3) + lo3]       = f2hbits(h0);
            aHu[(((wv << 4) + ((2 + hi) << 2) + quad) << 3) + lo3] = f2hbits(h1);

            // refill FIFO slot u with P(s+4)
            if (s + 4 < 128) { pA[u] = rp[n_0]; pB[u] = rp[n_1]; rbump(); }

            lds_barrier();
            buf ^= 1;
        }
    }

    // epilogue: P_next(cell(127)) from h(127)
    {
        half8 ahr[8];
#pragma unroll
        for (int f = 0; f < 8; ++f)
            ahr[f] = aH[buf][(f << 4) + (quad << 2) + lrow];
        float4v pn0 = {biasN0, biasN0, biasN0, biasN0};
        float4v pn1 = {biasN1, biasN1, biasN1, biasN1};
#pragma unroll
        for (int f = 0; f < 8; ++f) {
            pn0 = __builtin_amdgcn_mfma_f32_16x16x32_f16(ahr[f], BN0[f], pn0, 0, 0, 0);
            pn1 = __builtin_amdgcn_mfma_f32_16x16x32_f16(ahr[f], BN1[f], pn1, 0, 0, 0);
        }
        wp[n_0] = sel4(pn0, quad);
        wp[n_1] = sel4(pn1, quad);
    }
}

extern "C" __global__ void __launch_bounds__(512, 1)
grid_rnn2f_d0(const float* __restrict__ Wx_hh, const float* __restrict__ Wy_hh,
              const float* __restrict__ Wx_ih, const float* __restrict__ Wy_ih,
              const float* __restrict__ bx_ih, const float* __restrict__ bx_hh,
              const float* __restrict__ by_ih, const float* __restrict__ by_hh,
              float* __restrict__ out, const float* __restrict__ P0)
{ rnn2f_body<0>(Wx_hh, Wy_hh, Wx_ih, Wy_ih, bx_ih, bx_hh, by_ih, by_hh, out, P0); }

extern "C" __global__ void __launch_bounds__(512, 1)
grid_rnn2f_d1(const float* __restrict__ Wx_hh, const float* __restrict__ Wy_hh,
              const float* __restrict__ Wx_ih, const float* __restrict__ Wy_ih,
              const float* __restrict__ bx_ih, const float* __restrict__ bx_hh,
              const float* __restrict__ by_ih, const float* __restrict__ by_hh,
              float* __restrict__ out, const float* __restrict__ P0)
{ rnn2f_body<1>(Wx_hh, Wy_hh, Wx_ih, Wy_ih, bx_ih, bx_hh, by_ih, by_hh, out, P0); }

// ===================== final depth (d=2): h -> out =====================
extern "C" __global__ void __launch_bounds__(512, 2)
grid_rnn2_last(const float* __restrict__ Wx_hh, const float* __restrict__ Wy_hh,
               float* __restrict__ out)
{
    __shared__ half8 aH[2][128];

    const int tid  = threadIdx.x;
    const int lane = tid & 63;
    const int wv   = tid >> 6;
    const int quad = lane >> 4;
    const int l15  = lane & 15;
    const int lrow = lane & 3;

    const int bid  = blockIdx.x;
    const int isY  = bid >= 128;
    const int g    = isY ? bid - 128 : bid;
    const int b    = g >> 5;
    const int c0   = (g & 31) << 2;
    const int slot = isY;

    const float* Whh = (isY ? Wy_hh : Wx_hh) + (size_t)2 * HH * HH;

    const int n_0 = (wv << 5) + l15;
    const int n_1 = n_0 + 16;

    half8 Bhh0[8], Bhh1[8];
    {
        const float* r0 = Whh + (size_t)n_0 * HH;
        const float* r1 = Whh + (size_t)n_1 * HH;
#pragma unroll
        for (int f = 0; f < 8; ++f) {
            const int k = (f << 5) + (quad << 3);
            Bhh0[f] = ldfrag_f32(r0, k);
            Bhh1[f] = ldfrag_f32(r1, k);
        }
    }

    // ---- P read FIFO (chain = quad)
    float pA[4], pB[4];
    int rj = isY ? 0 : ((c0 + quad) & 127);
    const float* rp = out + (isY ? ((size_t)(b * SS + c0 + quad) * TT)
                                 : ((size_t)b * SS * TT + rj)) * 2 * HH
                          + (size_t)slot * HH;
    auto rbump = [&]() {
        if (isY) { rp += 2 * HH; }
        else { rp += (size_t)(rj == 127 ? 1 : 129) * 2 * HH; rj = (rj + 1) & 127; }
    };
#pragma unroll
    for (int u = 0; u < 4; ++u) { pA[u] = rp[n_0]; pB[u] = rp[n_1]; rbump(); }

    // ---- spread h-store: thread handles chain sm=tid>>7, floats kk,kk+1
    const int sm = tid >> 7;
    const int kk = (tid & 127) << 1;
    int sj = isY ? 0 : ((c0 + sm) & 127);
    float* sp = out + (isY ? ((size_t)(b * SS + c0 + sm) * TT)
                           : ((size_t)b * SS * TT + sj)) * 2 * HH
                    + (size_t)slot * HH + kk;
    const int rb32 = ((((kk >> 3) << 2) + sm) << 3 | (kk & 7)) >> 1;  // u32 idx in aH buf

    auto store_spread = [&](int bufi) {
        const unsigned int* a32 = (const unsigned int*)aH[bufi];
        const unsigned int w = a32[rb32];
        const _Float16 lo = __builtin_bit_cast(_Float16, (unsigned short)(w & 0xffff));
        const _Float16 hv = __builtin_bit_cast(_Float16, (unsigned short)(w >> 16));
        float2v t; t[0] = (float)lo; t[1] = (float)hv;
        *(float2v*)sp = t;
        if (isY) { sp += 2 * HH; }
        else { sp += (size_t)(sj == 127 ? 1 : 129) * 2 * HH; sj = (sj + 1) & 127; }
    };

    if (tid < 128) {
        half8 z;
#pragma unroll
        for (int e = 0; e < 8; ++e) z[e] = (_Float16)0.f;
        aH[0][tid] = z;
    }
    __syncthreads();

    const int hi  = l15 >> 3;
    const int lo3 = l15 & 7;

    int buf = 0;
    for (int s4 = 0; s4 < 128; s4 += 4) {
#pragma unroll
        for (int u = 0; u < 4; ++u) {
            const int s = s4 + u;

            if (s > 0) store_spread(buf);   // h(s-1) -> out (overwrites consumed P)

            half8 ahr[8];
#pragma unroll
            for (int f = 0; f < 8; ++f)
                ahr[f] = aH[buf][(f << 4) + (quad << 2) + lrow];

            float4v ah0 = {0.f, 0.f, 0.f, 0.f};
            float4v ah1 = {0.f, 0.f, 0.f, 0.f};
            __builtin_amdgcn_s_setprio(1);
#pragma unroll
            for (int f = 0; f < 8; ++f) {
                ah0 = __builtin_amdgcn_mfma_f32_16x16x32_f16(ahr[f], Bhh0[f], ah0, 0, 0, 0);
                ah1 = __builtin_amdgcn_mfma_f32_16x16x32_f16(ahr[f], Bhh1[f], ah1, 0, 0, 0);
            }
            __builtin_amdgcn_s_setprio(0);

            const float h0 = fast_tanh(sel4(ah0, quad) + pA[u]);
            const float h1 = fast_tanh(sel4(ah1, quad) + pB[u]);
            unsigned short* aHu = (unsigned short*)aH[buf ^ 1];
            aHu[(((wv << 4) + (hi << 2) + quad) << 3) + lo3]       = f2hbits(h0);
            aHu[(((wv << 4) + ((2 + hi) << 2) + quad) << 3) + lo3] = f2hbits(h1);

            if (s + 4 < 128) { pA[u] = rp[n_0]; pB[u] = rp[n_1]; rbump(); }

            lds_barrier();
            buf ^= 1;
        }
    }

    store_spread(buf);   // h(127)
}

// ===================== fallback (tiny ws): R8 v1 path =====================
template <int DI>
__device__ __forceinline__ void grid_rnn_body_v1(
    const float* __restrict__ src, const float* __restrict__ trg,
    const float* __restrict__ Wx_ih, const float* __restrict__ Wx_hh,
    const float* __restrict__ bx_ih, const float* __restrict__ bx_hh,
    const float* __restrict__ Wy_ih, const float* __restrict__ Wy_hh,
    const float* __restrict__ by_ih, const float* __restrict__ by_hh,
    float* __restrict__ out)
{
    __shared__ half8 aX[2][128];
    __shared__ half8 aH[2][128];

    const int tid  = threadIdx.x;
    const int lane = tid & 63;
    const int wv   = tid >> 6;
    const int quad = lane >> 4;
    const int l15  = lane & 15;

    const int bid  = blockIdx.x;
    const int isY  = bid >= 128;
    const int g    = isY ? bid - 128 : bid;
    const int b    = g >> 5;
    const int c0   = (g & 31) << 2;
    const int slot = isY;

    const float* Wih = (isY ? Wy_ih : Wx_ih) + (size_t)DI * HH * HH;
    const float* Whh = (isY ? Wy_hh : Wx_hh) + (size_t)DI * HH * HH;
    const float* bih = (isY ? by_ih : bx_ih) + DI * HH;
    const float* bhh = (isY ? by_hh : bx_hh) + DI * HH;

    const int n_0 = (wv << 5) + l15;
    const int n_1 = n_0 + 16;

    half8 Bih0[8], Bih1[8], Bhh0[8], Bhh1[8];
    {
        const float* r0i = Wih + (size_t)n_0 * HH;
        const float* r1i = Wih + (size_t)n_1 * HH;
        const float* r0h = Whh + (size_t)n_0 * HH;
        const float* r1h = Whh + (size_t)n_1 * HH;
#pragma unroll
        for (int f = 0; f < 8; ++f) {
            const int k = (f << 5) + (quad << 3);
            Bih0[f] = ldfrag_f32(r0i, k);
            Bih1[f] = ldfrag_f32(r1i, k);
            Bhh0[f] = ldfrag_f32(r0h, k);
            Bhh1[f] = ldfrag_f32(r1h, k);
        }
    }
    const float bias0 = bih[n_0] + bhh[n_0];
    const float bias1 = bih[n_1] + bhh[n_1];

    const int sact = (tid < 128);
    const int cm   = tid & 3;
    const int ck0  = (tid >> 2) << 3;
    const int chc  = c0 + cm;

    auto stage_now = [&](int sn) -> half8 {
        const int i = isY ? chc : sn;
        const int j = isY ? sn : ((chc + sn) & 127);
        const size_t cell = (size_t)(b * SS + i) * TT + j;
        half8 v;
        if constexpr (DI == 0) {
            const float* row = isY ? (trg + (size_t)(b * TT + j) * HH)
                                   : (src + (size_t)(b * SS + i) * HH);
            const float4v u0 = *(const float4v*)(row + ck0);
            const float4v u1 = *(const float4v*)(row + ck0 + 4);
#pragma unroll
            for (int e = 0; e < 4; ++e) { v[e] = (_Float16)u0[e]; v[4 + e] = (_Float16)u1[e]; }
        } else {
            const float* row = out + cell * 2 * HH + (size_t)slot * HH + ck0;
            const float4v u0 = *(const float4v*)(row);
            const float4v u1 = *(const float4v*)(row + 4);
#pragma unroll
            for (int e = 0; e < 4; ++e) { v[e] = (_Float16)u0[e]; v[4 + e] = (_Float16)u1[e]; }
        }
        return v;
    };

    auto store_h = [&](int sp, int bufi) {
        const half8 v = aH[bufi][tid];
        const int i = isY ? chc : sp;
        const int j = isY ? sp : ((chc + sp) & 127);
        const size_t cell = (size_t)(b * SS + i) * TT + j;
        float* p = out + cell * 2 * HH + (size_t)slot * HH + ck0;
        float4v u0, u1;
#pragma unroll
        for (int e = 0; e < 4; ++e) { u0[e] = (float)v[e]; u1[e] = (float)v[4 + e]; }
        *(float4v*)p = u0;
        *(float4v*)(p + 4) = u1;
    };

    if (sact) {
        half8 z;
#pragma unroll
        for (int e = 0; e < 8; ++e) z[e] = (_Float16)0.f;
        aH[0][tid] = z;
        aX[0][tid] = stage_now(0);
    }
    __syncthreads();

    const int lrow = lane & 3;

    int buf = 0;
    for (int s = 0; s < 128; ++s) {
        if (s > 0 && sact) store_h(s - 1, buf);
        if (sact) {
            int t = s + 1; if (t > 127) t = 127;
            aX[buf ^ 1][tid] = stage_now(t);
        }

        half8 axr[8], ahr[8];
#pragma unroll
        for (int f = 0; f < 8; ++f) {
            const int e = (f << 4) + (quad << 2) + lrow;
            axr[f] = aX[buf][e];
            ahr[f] = aH[buf][e];
        }

        float4v ax0 = {bias0, bias0, bias0, bias0};
        float4v ax1 = {bias1, bias1, bias1, bias1};
        float4v ah0 = {0.f, 0.f, 0.f, 0.f};
        float4v ah1 = {0.f, 0.f, 0.f, 0.f};
#pragma unroll
        for (int f = 0; f < 8; ++f) {
            ax0 = __builtin_amdgcn_mfma_f32_16x16x32_f16(axr[f], Bih0[f], ax0, 0, 0, 0);
            ax1 = __builtin_amdgcn_mfma_f32_16x16x32_f16(axr[f], Bih1[f], ax1, 0, 0, 0);
            ah0 = __builtin_amdgcn_mfma_f32_16x16x32_f16(ahr[f], Bhh0[f], ah0, 0, 0, 0);
            ah1 = __builtin_amdgcn_mfma_f32_16x16x32_f16(ahr[f], Bhh1[f], ah1, 0, 0, 0);
        }

        if (quad == 0) {
            unsigned short* aHu = (unsigned short*)aH[buf ^ 1];
            const int lo3 = lane & 7;
            const int hi  = lane >> 3;
#pragma unroll
            for (int r = 0; r < 4; ++r) {
                const float h0 = fast_tanh(ax0[r] + ah0[r]);
                const float h1 = fast_tanh(ax1[r] + ah1[r]);
                aHu[(wv << 7) + (hi << 5) + (r << 3) + lo3]       = f2hbits(h0);
                aHu[(wv << 7) + ((2 + hi) << 5) + (r << 3) + lo3] = f2hbits(h1);
            }
        }

        lds_barrier();
        buf ^= 1;
    }

    if (sact) store_h(127, buf);
}

extern "C" __global__ void __launch_bounds__(512, 2)
grid_rnn_v1_d0(const float* __restrict__ src, const float* __restrict__ trg,
               const float* __restrict__ Wx_ih, const float* __restrict__ Wx_hh,
               const float* __restrict__ bx_ih, const float* __restrict__ bx_hh,
               const float* __restrict__ Wy_ih, const float* __restrict__ Wy_hh,
               const float* __restrict__ by_ih, const float* __restrict__ by_hh,
               float* __restrict__ out)
{ grid_rnn_body_v1<0>(src, trg, Wx_ih, Wx_hh, bx_ih, bx_hh, Wy_ih, Wy_hh, by_ih, by_hh, out); }

extern "C" __global__ void __launch_bounds__(512, 2)
grid_rnn_v1_d1(const float* __restrict__ src, const float* __restrict__ trg,
               const float* __restrict__ Wx_ih, const float* __restrict__ Wx_hh,
               const float* __restrict__ bx_ih, const float* __restrict__ bx_hh,
               const float* __restrict__ Wy_ih, const float* __restrict__ Wy_hh,
               const float* __restrict__ by_ih, const float* __restrict__ by_hh,
               float* __restrict__ out)
{ grid_rnn_body_v1<1>(src, trg, Wx_ih, Wx_hh, bx_ih, bx_hh, Wy_ih, Wy_hh, by_ih, by_hh, out); }

extern "C" __global__ void __launch_bounds__(512, 2)
grid_rnn_v1_d2(const float* __restrict__ src, const float* __restrict__ trg,
               const float* __restrict__ Wx_ih, const float* __restrict__ Wx_hh,
               const float* __restrict__ bx_ih, const float* __restrict__ bx_hh,
               const float* __restrict__ Wy_ih, const float* __restrict__ Wy_hh,
               const float* __restrict__ by_ih, const float* __restrict__ by_hh,
               float* __restrict__ out)
{ grid_rnn_body_v1<2>(src, trg, Wx_ih, Wx_hh, bx_ih, bx_hh, Wy_ih, Wy_hh, by_ih, by_hh, out); }

// ===================== launch =====================
extern "C" void kernel_launch(void* const* d_in, const int* in_sizes, int n_in,
                              void* d_out, int out_size, void* d_ws, size_t ws_size,
                              hipStream_t stream) {
    const float* src   = (const float*)d_in[0];
    const float* trg   = (const float*)d_in[1];
    const float* Wx_ih = (const float*)d_in[2];
    const float* Wx_hh = (const float*)d_in[3];
    const float* bx_ih = (const float*)d_in[4];
    const float* bx_hh = (const float*)d_in[5];
    const float* Wy_ih = (const float*)d_in[6];
    const float* Wy_hh = (const float*)d_in[7];
    const float* by_ih = (const float*)d_in[8];
    const float* by_hh = (const float*)d_in[9];
    float* out = (float*)d_out;
    float* wsf = (float*)d_ws;

    const size_t needP0 = (size_t)2 * 131072 * sizeof(float);  // 1 MB

    if (ws_size >= needP0) {
        hipLaunchKernelGGL(grid_gemm0, dim3(16), dim3(512), 0, stream,
                           src, trg, Wx_ih, Wy_ih, bx_ih, bx_hh, by_ih, by_hh, wsf);
        hipLaunchKernelGGL(grid_rnn2f_d0, dim3(256), dim3(512), 0, stream,
                           Wx_hh, Wy_hh, Wx_ih, Wy_ih, bx_ih, bx_hh, by_ih, by_hh,
                           out, (const float*)wsf);
        hipLaunchKernelGGL(grid_rnn2f_d1, dim3(256), dim3(512), 0, stream,
                           Wx_hh, Wy_hh, Wx_ih, Wy_ih, bx_ih, bx_hh, by_ih, by_hh,
                           out, (const float*)wsf);
        hipLaunchKernelGGL(grid_rnn2_last, dim3(256), dim3(512), 0, stream,
                           Wx_hh, Wy_hh, out);
    } else {
        hipLaunchKernelGGL(grid_rnn_v1_d0, dim3(256), dim3(512), 0, stream,
                           src, trg, Wx_ih, Wx_hh, bx_ih, bx_hh,
                           Wy_ih, Wy_hh, by_ih, by_hh, out);
        hipLaunchKernelGGL(grid_rnn_v1_d1, dim3(256), dim3(512), 0, stream,
                           src, trg, Wx_ih, Wx_hh, bx_ih, bx_hh,
                           Wy_ih, Wy_hh, by_ih, by_hh, out);
        hipLaunchKernelGGL(grid_rnn_v1_d2, dim3(256), dim3(512), 0, stream,
                           src, trg, Wx_ih, Wx_hh, bx_ih, bx_hh,
                           Wy_ih, Wy_hh, by_ih, by_hh, out);
    }
}